// Round 1
// baseline (230.103 us; speedup 1.0000x reference)
//
#include <hip/hip_runtime.h>
#include <cstdint>
#include <cstddef>

#define NN 8192
#define NE 131072
#define EMB 256

typedef float f32x4 __attribute__((ext_vector_type(4)));
typedef __bf16 bf16x8 __attribute__((ext_vector_type(8)));

__device__ __forceinline__ unsigned short f2bf(float f) {
  unsigned u = __float_as_uint(f);
  u += 0x7fffu + ((u >> 16) & 1u);   // round-to-nearest-even
  return (unsigned short)(u >> 16);
}

__device__ __forceinline__ void gload_lds16(const void* g, void* l) {
  __builtin_amdgcn_global_load_lds(
      (const __attribute__((address_space(1))) unsigned int*)g,
      (__attribute__((address_space(3))) unsigned int*)l, 16, 0, 0);
}

// ---------- prep: node_emb f32 -> bf16 (row-major) + exact f32 sq-norms ----------
__global__ __launch_bounds__(256) void prep_kernel(const float* __restrict__ X,
                                                   unsigned short* __restrict__ Xb,
                                                   float* __restrict__ sq) {
  int row  = blockIdx.x * 4 + (threadIdx.x >> 6);
  int lane = threadIdx.x & 63;
  float4 v = ((const float4*)(X + (size_t)row * EMB))[lane];
  float s = v.x * v.x + v.y * v.y + v.z * v.z + v.w * v.w;
  #pragma unroll
  for (int off = 32; off > 0; off >>= 1) s += __shfl_down(s, off);
  if (lane == 0) sq[row] = s;
  ushort4 b;
  b.x = f2bf(v.x); b.y = f2bf(v.y); b.z = f2bf(v.z); b.w = f2bf(v.w);
  ((ushort4*)(Xb + (size_t)row * EMB))[lane] = b;
}

// ---------- node head: [8192x256] @ [256x64]^T + bias, f32 ----------
// 16 nodes/block, thread = (node e = tid>>4, 4 outputs o0=(tid&15)*4)
__global__ __launch_bounds__(256) void node_head_kernel(const float* __restrict__ X,
                                                        const float* __restrict__ w,
                                                        const float* __restrict__ bias,
                                                        float* __restrict__ out) {
  __shared__ float xs[16 * 68];
  int tid = threadIdx.x;
  int n0  = blockIdx.x * 16;
  int e   = tid >> 4;
  int o0  = (tid & 15) * 4;
  float acc[4] = {0.f, 0.f, 0.f, 0.f};
  for (int kc = 0; kc < 4; ++kc) {
    __syncthreads();
    {
      int r = tid >> 4, c = (tid & 15) * 4;
      float4 v = *(const float4*)(X + (size_t)(n0 + r) * EMB + kc * 64 + c);
      *(float4*)(&xs[r * 68 + c]) = v;
    }
    __syncthreads();
    #pragma unroll 4
    for (int k = 0; k < 64; k += 4) {
      float4 x = *(const float4*)(&xs[e * 68 + k]);
      int kk = kc * 64 + k;
      #pragma unroll
      for (int oo = 0; oo < 4; ++oo) {
        float4 wv = *(const float4*)(w + (size_t)(o0 + oo) * EMB + kk);
        acc[oo] = fmaf(x.x, wv.x, fmaf(x.y, wv.y, fmaf(x.z, wv.z, fmaf(x.w, wv.w, acc[oo]))));
      }
    }
  }
  float4 r;
  r.x = acc[0] + bias[o0 + 0];
  r.y = acc[1] + bias[o0 + 1];
  r.z = acc[2] + bias[o0 + 2];
  r.w = acc[3] + bias[o0 + 3];
  *(float4*)(out + (size_t)(n0 + e) * 64 + o0) = r;
}

// ---------- edge head: [131072x256] @ [256x16]^T + bias, f32 ----------
// 256 edges/block, thread owns one edge + all 16 outputs; w via wave-uniform scalar loads
__global__ __launch_bounds__(256) void edge_head_kernel(const float* __restrict__ X,
                                                        const float* __restrict__ w,
                                                        const float* __restrict__ bias,
                                                        float* __restrict__ out) {
  __shared__ float xs[256 * 33];   // stride 33 -> conflict-free per-lane row reads
  int tid = threadIdx.x;
  int e0  = blockIdx.x * 256;
  float acc[16];
  #pragma unroll
  for (int o = 0; o < 16; ++o) acc[o] = 0.f;
  for (int kc = 0; kc < 8; ++kc) {
    __syncthreads();
    #pragma unroll
    for (int it = 0; it < 8; ++it) {
      int f = it * 1024 + tid * 4;
      int r = f >> 5, c = f & 31;
      float4 v = *(const float4*)(X + (size_t)(e0 + r) * EMB + kc * 32 + c);
      float* d = &xs[r * 33 + c];
      d[0] = v.x; d[1] = v.y; d[2] = v.z; d[3] = v.w;
    }
    __syncthreads();
    #pragma unroll 4
    for (int k = 0; k < 32; ++k) {
      float x = xs[tid * 33 + k];
      const float* wk = w + kc * 32 + k;   // uniform address -> s_load
      #pragma unroll
      for (int o = 0; o < 16; ++o)
        acc[o] = fmaf(x, wk[(size_t)o * EMB], acc[o]);
    }
  }
  #pragma unroll
  for (int o = 0; o < 16; ++o) acc[o] += bias[o];
  float4* dst = (float4*)(out + (size_t)(e0 + tid) * 16);
  dst[0] = make_float4(acc[0], acc[1], acc[2], acc[3]);
  dst[1] = make_float4(acc[4], acc[5], acc[6], acc[7]);
  dst[2] = make_float4(acc[8], acc[9], acc[10], acc[11]);
  dst[3] = make_float4(acc[12], acc[13], acc[14], acc[15]);
}

// ---------- adj: sigmoid(W*(|xi|^2+|xj|^2-2 xi.xj)+b), zero diag ----------
// 128x128 tile/block, 4 waves (2x2), 16x16x32 bf16 MFMA, BK=64, K=256.
// LDS linear dest + inverse-swizzled global source + swizzled ds_read (rule #21).
__global__ __launch_bounds__(256) void adj_kernel(const unsigned short* __restrict__ Xb,
                                                  const float* __restrict__ sq,
                                                  const float* __restrict__ Wp,
                                                  const float* __restrict__ bp,
                                                  float* __restrict__ out) {
  __shared__ unsigned short As[128 * 64];
  __shared__ unsigned short Bs[128 * 64];

  int bid = blockIdx.x;
  int swz = (bid & 7) * 512 + (bid >> 3);   // XCD swizzle, nwg=4096 divisible by 8
  int ti = swz >> 6, tj = swz & 63;

  int tid  = threadIdx.x;
  int wave = tid >> 6, lane = tid & 63;
  int wr = (wave >> 1) * 64;   // wave row origin in tile
  int wc = (wave & 1) * 64;    // wave col origin in tile

  f32x4 acc[4][4] = {};

  int r_base = tid >> 3;         // + it*32
  int cb     = (tid & 7) << 4;   // byte col within 128B LDS row

  for (int kt = 0; kt < 4; ++kt) {
    #pragma unroll
    for (int it = 0; it < 4; ++it) {
      int r   = it * 32 + r_base;
      int cbs = cb ^ ((r & 7) << 4);            // inverse-swizzled source col
      int col = (kt << 6) + (cbs >> 1);
      const unsigned short* ga = Xb + (size_t)(ti * 128 + r) * EMB + col;
      const unsigned short* gb = Xb + (size_t)(tj * 128 + r) * EMB + col;
      gload_lds16(ga, (char*)As + it * 4096 + wave * 1024);
      gload_lds16(gb, (char*)Bs + it * 4096 + wave * 1024);
    }
    __syncthreads();
    #pragma unroll
    for (int ks = 0; ks < 2; ++ks) {
      bf16x8 af[4], bfr[4];
      #pragma unroll
      for (int m = 0; m < 4; ++m) {
        int rr = wr + m * 16 + (lane & 15);
        int bc = ((ks << 6) + ((lane >> 4) << 4)) ^ ((rr & 7) << 4);
        af[m] = *(const bf16x8*)((const char*)As + rr * 128 + bc);
      }
      #pragma unroll
      for (int n = 0; n < 4; ++n) {
        int rr = wc + n * 16 + (lane & 15);
        int bc = ((ks << 6) + ((lane >> 4) << 4)) ^ ((rr & 7) << 4);
        bfr[n] = *(const bf16x8*)((const char*)Bs + rr * 128 + bc);
      }
      #pragma unroll
      for (int m = 0; m < 4; ++m)
        #pragma unroll
        for (int n = 0; n < 4; ++n)
          acc[m][n] = __builtin_amdgcn_mfma_f32_16x16x32_bf16(af[m], bfr[n], acc[m][n], 0, 0, 0);
    }
    __syncthreads();
  }

  // epilogue: logit = W*(sq_i + sq_j) + b - 2W*dot ; sigmoid ; zero diagonal
  float W0 = Wp[0], b0 = bp[0];
  float w2 = -2.0f * W0;
  int col0  = tj * 128 + wc + (lane & 15);
  int row0g = ti * 128 + wr + ((lane >> 4) << 2);

  float ai[16];
  #pragma unroll
  for (int m = 0; m < 4; ++m)
    #pragma unroll
    for (int rg = 0; rg < 4; ++rg)
      ai[m * 4 + rg] = fmaf(W0, sq[row0g + m * 16 + rg], b0);

  #pragma unroll
  for (int n = 0; n < 4; ++n) {
    int j = col0 + n * 16;
    float sjW = W0 * sq[j];
    #pragma unroll
    for (int m = 0; m < 4; ++m) {
      #pragma unroll
      for (int rg = 0; rg < 4; ++rg) {
        int i = row0g + m * 16 + rg;
        float t = fmaf(w2, acc[m][n][rg], ai[m * 4 + rg] + sjW);
        float p = 1.0f / (1.0f + __expf(-t));
        if (i == j) p = 0.0f;
        out[(size_t)i * NN + j] = p;
      }
    }
  }
}

extern "C" void kernel_launch(void* const* d_in, const int* in_sizes, int n_in,
                              void* d_out, int out_size, void* d_ws, size_t ws_size,
                              hipStream_t stream) {
  const float* node_emb = (const float*)d_in[0];
  const float* edge_emb = (const float*)d_in[1];
  const float* node_w   = (const float*)d_in[2];
  const float* node_b   = (const float*)d_in[3];
  const float* edge_w   = (const float*)d_in[4];
  const float* edge_b   = (const float*)d_in[5];
  const float* Wp       = (const float*)d_in[6];
  const float* bp       = (const float*)d_in[7];

  float* out      = (float*)d_out;
  float* node_out = out;                        // [8192 x 64]
  float* edge_out = out + (size_t)NN * 64;      // [131072 x 16]
  float* adj_out  = out + (size_t)NN * 64 + (size_t)NE * 16;  // [8192 x 8192]

  unsigned short* Xb = (unsigned short*)d_ws;                       // 4 MiB
  float* sq = (float*)((char*)d_ws + (size_t)NN * EMB * 2);         // 32 KiB

  prep_kernel<<<dim3(NN / 4), dim3(256), 0, stream>>>(node_emb, Xb, sq);
  node_head_kernel<<<dim3(NN / 16), dim3(256), 0, stream>>>(node_emb, node_w, node_b, node_out);
  edge_head_kernel<<<dim3(NE / 256), dim3(256), 0, stream>>>(edge_emb, edge_w, edge_b, edge_out);
  adj_kernel<<<dim3(64 * 64), dim3(256), 0, stream>>>(Xb, sq, Wp, bp, adj_out);
}